// Round 10
// baseline (486.404 us; speedup 1.0000x reference)
//
#include <hip/hip_runtime.h>

#define BB 256
#define TT 512
#define NN 128
#define GO_IDX 1
#define EOS_IDX 2
#define TSPLIT 368            // bp steps t in [1,TSPLIT) in LDS; [TSPLIT,512) spilled (ws or consumed unary rows)
#define NEGV (-10000.0f)
// padded alpha slot: x + (x>>5)*4  -> quarter bases at 0,36,72,108 (banks 0,4,8,12; 16B aligned)
#define ASLOT(x) ((x) + (((x) >> 5) << 2))

// step barrier: drain LDS only (alpha/bps/prob), leave global prefetch loads in flight.
#define STEP_BARRIER() asm volatile("s_waitcnt lgkmcnt(0)\n\ts_barrier" ::: "memory")

// ---------- DPP quad_perm helpers ----------
__device__ __forceinline__ float dpp_xor1_f(float x) {      // quad_perm [1,0,3,2]
    return __int_as_float(__builtin_amdgcn_update_dpp(0, __float_as_int(x), 0xB1, 0xF, 0xF, true));
}
__device__ __forceinline__ float dpp_xor2_f(float x) {      // quad_perm [2,3,0,1]
    return __int_as_float(__builtin_amdgcn_update_dpp(0, __float_as_int(x), 0x4E, 0xF, 0xF, true));
}
__device__ __forceinline__ int dpp_xor1_i(int x) {
    return __builtin_amdgcn_update_dpp(0, x, 0xB1, 0xF, 0xF, true);
}
__device__ __forceinline__ int dpp_xor2_i(int x) {
    return __builtin_amdgcn_update_dpp(0, x, 0x4E, 0xF, 0xF, true);
}

// ---------- fused kernel: in-flight log_softmax + serial Viterbi ----------
// Round-10 change (bit-exact): software-pipelined backpointer extraction.
// Per step, ONLY the value path runs before the barrier (adds + fmax tree +
// DPP fmax + alpha write); the 32 raw sums are carried in registers (cv[]).
// The (val,idx) comparison network (identical to the round-9 proven tree +
// DPP tie-break) is replayed on cv[] at the TOP of the NEXT step, under the
// shadow of that step's ds_read latency, and the bps store happens there.
// bps is write-only during the forward pass, so deferring its store by one
// step is safe; the last step's carry is flushed after the loop.
// USE_WS=1: bp spill to d_ws; USE_WS=0: spill into consumed unary rows.
template <int USE_WS>
__global__ __launch_bounds__(512) void viterbi_kernel(
    float* __restrict__ u,               // [B,T,N] RAW unaries
    const float* __restrict__ trans,     // [1,N,N] trans0[cur][prev]
    const int*   __restrict__ lengths_raw,
    float* __restrict__ out,             // [B*T] preds then [B] scores
    unsigned char* __restrict__ ws)      // spill: [B][144][128] bytes when USE_WS
{
    __shared__ unsigned char bps[(TSPLIT - 1) * NN];   // 46976 B (steps 1..367 at row t-1)
    __shared__ __align__(16) float prob[2][16][NN];    // 16384 B, normalized rows (dbuf); reused as bp cache
    __shared__ __align__(16) float alpha[2][144];      // 1152 B; reused as last_tag/H tables in epilogue
    __shared__ float fin_v[2];
    __shared__ int   fin_i[2];

    const int tid  = threadIdx.x;
    const int b    = blockIdx.x;
    const int wave = tid >> 6;
    const int lane = tid & 63;
    const int q    = tid & 3;              // prev-quarter owned by this lane
    const int cur  = tid >> 2;             // tag owned by this quad (0..127)
    const int hw   = tid >> 5;             // half-wave id 0..15 (lsm row owner)
    const int l32  = tid & 31;

    int len;
    {
        int probe = lengths_raw[1];        // ==0 iff int64 (lengths >= 256 > 0)
        len = (probe == 0) ? lengths_raw[2 * b] : lengths_raw[b];
    }

    float* pb = u + (size_t)b * TT * NN;
    const float4* pb4 = (const float4*)pb;
    unsigned char* spb = USE_WS ? (ws + (size_t)b * ((TT - TSPLIT) * NN)) : (unsigned char*)pb;

    // trans chunk in registers: trans0[cur][q*32 + j], j in [0,32)
    float tr[32];
    {
        const float4* t4 = (const float4*)(trans + cur * NN + q * 32);
#pragma unroll
        for (int i = 0; i < 8; ++i) {
            float4 v = t4[i];
            tr[4*i+0] = v.x; tr[4*i+1] = v.y; tr[4*i+2] = v.z; tr[4*i+3] = v.w;
        }
    }

    if (tid < NN) alpha[0][ASLOT(tid)] = (tid == GO_IDX) ? 0.0f : NEGV;

    // per-row log_softmax, bitwise-identical to the proven math
    auto normrow = [&](float4 v, float* dstrow) {
        float m = fmaxf(fmaxf(v.x, v.y), fmaxf(v.z, v.w));
#pragma unroll
        for (int off = 16; off; off >>= 1) m = fmaxf(m, __shfl_xor(m, off, 64));
        float s = expf(v.x - m) + expf(v.y - m) + expf(v.z - m) + expf(v.w - m);
#pragma unroll
        for (int off = 16; off; off >>= 1) s += __shfl_xor(s, off, 64);
        float ls = logf(s);
        ((float4*)dstrow)[l32] =
            make_float4((v.x - m) - ls, (v.y - m) - ls, (v.z - m) - ls, (v.w - m) - ls);
    };

    // carried state: raw sums of the previous step (cv) + its step index
    float cv[32];
    int   c_t = 0;                         // 0 => nothing to store (t>=1 required)

    // deferred bp extraction: EXACT round-9 (val,idx) network on cv[],
    // then the proven DPP quad tie-break, then the bps store.
    auto bp_shadow = [&](int ct) {
        float m1[16]; int i1[16];
#pragma unroll
        for (int j = 0; j < 16; ++j) {
            bool tk = cv[2*j+1] > cv[2*j];
            m1[j] = tk ? cv[2*j+1] : cv[2*j];
            i1[j] = tk ? 2*j+1 : 2*j;
        }
        float m2[8]; int i2[8];
#pragma unroll
        for (int j = 0; j < 8; ++j) {
            bool tk = m1[2*j+1] > m1[2*j];
            m2[j] = tk ? m1[2*j+1] : m1[2*j];
            i2[j] = tk ? i1[2*j+1] : i1[2*j];
        }
        float m3[4]; int i3[4];
#pragma unroll
        for (int j = 0; j < 4; ++j) {
            bool tk = m2[2*j+1] > m2[2*j];
            m3[j] = tk ? m2[2*j+1] : m2[2*j];
            i3[j] = tk ? i2[2*j+1] : i2[2*j];
        }
        float m4[2]; int i4[2];
#pragma unroll
        for (int j = 0; j < 2; ++j) {
            bool tk = m3[2*j+1] > m3[2*j];
            m4[j] = tk ? m3[2*j+1] : m3[2*j];
            i4[j] = tk ? i3[2*j+1] : i3[2*j];
        }
        bool tk5 = m4[1] > m4[0];
        float best = tk5 ? m4[1] : m4[0];
        int   bp   = (tk5 ? i4[1] : i4[0]) + q * 32;   // absolute prev index

        float v1 = dpp_xor1_f(best); int b1 = dpp_xor1_i(bp);
        bool  t1 = (q & 1) ? (v1 >= best) : (v1 > best);
        float mm1 = t1 ? v1 : best;  int p1 = t1 ? b1 : bp;
        float v2 = dpp_xor2_f(mm1);  int b2 = dpp_xor2_i(p1);
        bool  t2 = (q & 2) ? (v2 >= mm1) : (v2 > mm1);
        int BP = t2 ? b2 : p1;

        if (q == 0 && ct >= 1) {
            if (ct < TSPLIT) bps[(ct - 1) * NN + cur] = (unsigned char)BP;
            else if (USE_WS) spb[(ct - TSPLIT) * NN + cur] = (unsigned char)BP;
            else             spb[(size_t)ct * 512 + cur] = (unsigned char)BP;
        }
    };

    // prologue: rows 0..15 -> buf0; rows 16..31 -> R (normalized at top of g=0)
    float4 R = pb4[hw * 32 + l32];
    normrow(R, &prob[0][hw][0]);
    R = pb4[(16 + hw) * 32 + l32];
    __syncthreads();

    const int nG = (len + 15) >> 4;
    for (int g = 0; g < nG; ++g) {
        const int tb = g << 4;
        // Pv register prefetch for the whole group (written during g-1, synced)
        float Pg[16];
#pragma unroll
        for (int k2 = 0; k2 < 16; ++k2) Pg[k2] = prob[g & 1][k2][cur];
        // normalize rows of group g+1 (loaded last group) -> buf[(g+1)&1].
        normrow(R, &prob[(g + 1) & 1][hw][0]);
        // issue raw loads for group g+2 (stay in flight across step barriers)
        {
            int rr = tb + 32 + hw;
            if (rr > TT - 1) rr = TT - 1;   // clamped row never normalized/used
            R = pb4[rr * 32 + l32];
        }
#pragma unroll 4
        for (int k = 0; k < 16; ++k) {
            const int t = tb + k;
            if (t < len) {                         // uniform per block
                const float* ra = alpha[t & 1];
                float*       wa = alpha[(t & 1) ^ 1];
                const float4* a4 = (const float4*)(ra + q * 36);  // banks 0/4/8/12 per quarter
                // issue the 8 alpha reads first...
                float4 av[8];
#pragma unroll
                for (int i = 0; i < 8; ++i) av[i] = a4[i];
                // ...and extract the PREVIOUS step's backpointer under their latency
                if (t > 0) bp_shadow(c_t);
                // 32 adds into the carry array (same values as proven version)
#pragma unroll
                for (int i = 0; i < 8; ++i) {
                    cv[4*i+0] = av[i].x + tr[4*i+0];
                    cv[4*i+1] = av[i].y + tr[4*i+1];
                    cv[4*i+2] = av[i].z + tr[4*i+2];
                    cv[4*i+3] = av[i].w + tr[4*i+3];
                }
                // value-only balanced fmax tree (same max value, fused to max3)
                float w0[16];
#pragma unroll
                for (int j = 0; j < 16; ++j) w0[j] = fmaxf(cv[2*j], cv[2*j+1]);
                float w1[4];
#pragma unroll
                for (int j = 0; j < 4; ++j)
                    w1[j] = fmaxf(fmaxf(w0[4*j], w0[4*j+1]), fmaxf(w0[4*j+2], w0[4*j+3]));
                float best = fmaxf(fmaxf(w1[0], w1[1]), fmaxf(w1[2], w1[3]));
                float mq = fmaxf(best, dpp_xor1_f(best));
                float M  = fmaxf(mq, dpp_xor2_f(mq));

                if (q == 0) wa[ASLOT(cur)] = M + Pg[k];
                c_t = t;
                STEP_BARRIER();    // lgkmcnt(0) only — global prefetch stays in flight
            }
        }
    }

    // flush the last step's backpointer
    bp_shadow(c_t);

    __threadfence();   // spilled bp global writes visible to this block's readers

    // terminal: argmax(alpha + trans0[EOS][:]), first-max tie-break
    if (tid < NN) {
        float v = alpha[len & 1][ASLOT(tid)] + trans[EOS_IDX * NN + tid];
        int idx = tid;
#pragma unroll
        for (int off = 32; off; off >>= 1) {
            float ov = __shfl_xor(v, off, 64);
            int   oi = __shfl_xor(idx, off, 64);
            if (ov > v || (ov == v && oi < idx)) { v = ov; idx = oi; }
        }
        if (lane == 0) { fin_v[wave] = v; fin_i[wave] = idx; }
    }
    __syncthreads();   // fin ready; full drain (incl. vmcnt) of forward traffic

    const int lenU = __builtin_amdgcn_readfirstlane(len);

    for (int t = lenU + tid; t < TT; t += 512) out[(size_t)b * TT + t] = 0.0f;

    // stage spilled bp steps [TSPLIT, TSPLIT+128) into the (now free) prob LDS.
    {
        unsigned int* cache = (unsigned int*)&prob[0][0][0];          // 16384 B, exact fit
        const volatile unsigned int* src = (const volatile unsigned int*)spb;
        for (int i = tid; i < 128 * 32; i += 512) {
            if (USE_WS) cache[i] = src[(size_t)(i >> 5) * 32 + (i & 31)];
            else        cache[i] = src[(size_t)(TSPLIT + (i >> 5)) * 128 + (i & 31)];
        }
    }
    __syncthreads();

    // terminal winner (uniform across threads)
    float sc; int T0;
    {
        float v0 = fin_v[0], v1 = fin_v[1];
        int   i0 = fin_i[0], i1 = fin_i[1];
        if (v1 > v0) { sc = v1; T0 = i1; }
        else         { sc = v0; T0 = i0; }
    }
    if (tid == 0) {
        out[(size_t)BB * TT + b] = sc;
        out[(size_t)b * TT + (lenU - 1)] = (float)T0;
    }

    // ---------- parallel hypothesis backtrace ----------
    // 8 segments of 64 links; wave s chases segment s for all 128 entry tags
    // (2 hypotheses/lane), replaying the exact same byte loads as a serial chase.
    const unsigned char* cacheb = (const unsigned char*)&prob[0][0][0];
    unsigned char* lt   = (unsigned char*)&alpha[0][0];   // last_tag[8][128] overlay (alpha dead)
    unsigned char* Harr = lt + 1024;                      // H[8] overlay

    const int s  = wave;                   // segment id 0..7
    const int A  = lenU - 1 - 64 * s;      // anchor time of this segment
    const int h0 = lane;                   // hypothesis tags
    const int h1 = 64 + lane;
    const int Jmax = (A < 64) ? A : 64;    // links to follow (A<1 -> none)

    unsigned int rec0[16], rec1[16];
#pragma unroll
    for (int i = 0; i < 16; ++i) { rec0[i] = 0u; rec1[i] = 0u; }

    int c0 = h0, c1 = h1;
#pragma unroll
    for (int j = 1; j <= 64; ++j) {
        if (j <= Jmax) {                   // wave-uniform
            const int x = A - j + 1;       // step whose bp we read -> tag at time A-j
            int n0, n1;
            if (x < TSPLIT) {
                n0 = bps[(x - 1) * NN + c0];
                n1 = bps[(x - 1) * NN + c1];
            } else if (x < TSPLIT + 128) {
                n0 = cacheb[(x - TSPLIT) * NN + c0];
                n1 = cacheb[(x - TSPLIT) * NN + c1];
            } else {
                if (USE_WS) {
                    n0 = ((const volatile unsigned char*)spb)[(size_t)(x - TSPLIT) * NN + c0];
                    n1 = ((const volatile unsigned char*)spb)[(size_t)(x - TSPLIT) * NN + c1];
                } else {
                    n0 = ((const volatile unsigned char*)spb)[(size_t)x * 512 + c0];
                    n1 = ((const volatile unsigned char*)spb)[(size_t)x * 512 + c1];
                }
            }
            c0 = n0; c1 = n1;
            rec0[(j - 1) >> 2] |= (unsigned int)c0 << (((j - 1) & 3) * 8);
            rec1[(j - 1) >> 2] |= (unsigned int)c1 << (((j - 1) & 3) * 8);
        }
    }
    if (A >= 65) {                         // tag at A-64 feeds segment s+1's stitch
        lt[s * NN + h0] = (unsigned char)c0;
        lt[s * NN + h1] = (unsigned char)c1;
    }
    __syncthreads();

    if (tid == 0) {
        int H = T0;
        Harr[0] = (unsigned char)H;
#pragma unroll
        for (int ss = 1; ss < 8; ++ss) {
            if (lenU - 1 - 64 * ss >= 1) {
                H = lt[(ss - 1) * NN + H];
                Harr[ss] = (unsigned char)H;
            }
        }
    }
    __syncthreads();

    if (A >= 1) {
        const int Hs = Harr[s];
        if (h0 == Hs) {
#pragma unroll
            for (int j = 1; j <= 64; ++j)
                if (j <= Jmax)
                    out[(size_t)b * TT + (A - j)] =
                        (float)((rec0[(j - 1) >> 2] >> (((j - 1) & 3) * 8)) & 255u);
        }
        if (h1 == Hs) {
#pragma unroll
            for (int j = 1; j <= 64; ++j)
                if (j <= Jmax)
                    out[(size_t)b * TT + (A - j)] =
                        (float)((rec1[(j - 1) >> 2] >> (((j - 1) & 3) * 8)) & 255u);
        }
    }
}

extern "C" void kernel_launch(void* const* d_in, const int* in_sizes, int n_in,
                              void* d_out, int out_size, void* d_ws, size_t ws_size,
                              hipStream_t stream) {
    float*       unaries = (float*)d_in[0];
    const float* trans   = (const float*)d_in[1];
    const int*   lengths = (const int*)d_in[2];
    float* out = (float*)d_out;
    unsigned char* ws = (unsigned char*)d_ws;

    const size_t need = (size_t)BB * (TT - TSPLIT) * NN;   // 4,718,592 B
    if (ws != nullptr && ws_size >= need) {
        hipLaunchKernelGGL(HIP_KERNEL_NAME(viterbi_kernel<1>), dim3(BB), dim3(512), 0, stream,
                           unaries, trans, lengths, out, ws);
    } else {
        hipLaunchKernelGGL(HIP_KERNEL_NAME(viterbi_kernel<0>), dim3(BB), dim3(512), 0, stream,
                           unaries, trans, lengths, out, ws);
    }
}

// Round 11
// 462.484 us; speedup vs baseline: 1.0517x; 1.0517x over previous
//
#include <hip/hip_runtime.h>

#define BB 256
#define TT 512
#define NN 128
#define GO_IDX 1
#define EOS_IDX 2
#define TSPLIT 368            // bp steps t in [1,TSPLIT) in LDS; [TSPLIT,512) spilled (ws or consumed unary rows)
#define NEGV (-10000.0f)
// padded alpha slot: x + (x>>5)*4  -> quarter bases at 0,36,72,108 (banks 0,4,8,12; 16B aligned)
#define ASLOT(x) ((x) + (((x) >> 5) << 2))

// step barrier: drain LDS only (alpha/bps/prob), leave global prefetch loads in flight.
#define STEP_BARRIER() asm volatile("s_waitcnt lgkmcnt(0)\n\ts_barrier" ::: "memory")

// ---------- DPP quad_perm helpers ----------
__device__ __forceinline__ float dpp_xor1_f(float x) {      // quad_perm [1,0,3,2]
    return __int_as_float(__builtin_amdgcn_update_dpp(0, __float_as_int(x), 0xB1, 0xF, 0xF, true));
}
__device__ __forceinline__ float dpp_xor2_f(float x) {      // quad_perm [2,3,0,1]
    return __int_as_float(__builtin_amdgcn_update_dpp(0, __float_as_int(x), 0x4E, 0xF, 0xF, true));
}
__device__ __forceinline__ int dpp_xor1_i(int x) {
    return __builtin_amdgcn_update_dpp(0, x, 0xB1, 0xF, 0xF, true);
}
__device__ __forceinline__ int dpp_xor2_i(int x) {
    return __builtin_amdgcn_update_dpp(0, x, 0x4E, 0xF, 0xF, true);
}

// ---------- fused kernel: in-flight log_softmax + serial Viterbi ----------
// Round-9 proven optimum (restored). Structure: round-2 single-chain 512-thread
// lockstep + (a) bit-exact (val,idx) tree reduction (serial first-max == tree
// with strict-> toward the higher-index arm), (b) group-top Pv register
// prefetch. Compiler schedules value-chain + alpha write first; index selects
// fill pre-barrier slack (R10 proved forcing any other order costs 1:1).
// USE_WS=1: bp spill to d_ws; USE_WS=0: spill into consumed unary rows.
template <int USE_WS>
__global__ __launch_bounds__(512) void viterbi_kernel(
    float* __restrict__ u,               // [B,T,N] RAW unaries
    const float* __restrict__ trans,     // [1,N,N] trans0[cur][prev]
    const int*   __restrict__ lengths_raw,
    float* __restrict__ out,             // [B*T] preds then [B] scores
    unsigned char* __restrict__ ws)      // spill: [B][144][128] bytes when USE_WS
{
    __shared__ unsigned char bps[(TSPLIT - 1) * NN];   // 46976 B (steps 1..367 at row t-1)
    __shared__ __align__(16) float prob[2][16][NN];    // 16384 B, normalized rows (dbuf); reused as bp cache
    __shared__ __align__(16) float alpha[2][144];      // 1152 B; reused as last_tag/H tables in epilogue
    __shared__ float fin_v[2];
    __shared__ int   fin_i[2];

    const int tid  = threadIdx.x;
    const int b    = blockIdx.x;
    const int wave = tid >> 6;
    const int lane = tid & 63;
    const int q    = tid & 3;              // prev-quarter owned by this lane
    const int cur  = tid >> 2;             // tag owned by this quad (0..127)
    const int hw   = tid >> 5;             // half-wave id 0..15 (lsm row owner)
    const int l32  = tid & 31;

    int len;
    {
        int probe = lengths_raw[1];        // ==0 iff int64 (lengths >= 256 > 0)
        len = (probe == 0) ? lengths_raw[2 * b] : lengths_raw[b];
    }

    float* pb = u + (size_t)b * TT * NN;
    const float4* pb4 = (const float4*)pb;
    unsigned char* spb = USE_WS ? (ws + (size_t)b * ((TT - TSPLIT) * NN)) : (unsigned char*)pb;

    // trans chunk in registers: trans0[cur][q*32 + j], j in [0,32)
    float tr[32];
    {
        const float4* t4 = (const float4*)(trans + cur * NN + q * 32);
#pragma unroll
        for (int i = 0; i < 8; ++i) {
            float4 v = t4[i];
            tr[4*i+0] = v.x; tr[4*i+1] = v.y; tr[4*i+2] = v.z; tr[4*i+3] = v.w;
        }
    }

    if (tid < NN) alpha[0][ASLOT(tid)] = (tid == GO_IDX) ? 0.0f : NEGV;

    // per-row log_softmax, bitwise-identical to the proven math
    auto normrow = [&](float4 v, float* dstrow) {
        float m = fmaxf(fmaxf(v.x, v.y), fmaxf(v.z, v.w));
#pragma unroll
        for (int off = 16; off; off >>= 1) m = fmaxf(m, __shfl_xor(m, off, 64));
        float s = expf(v.x - m) + expf(v.y - m) + expf(v.z - m) + expf(v.w - m);
#pragma unroll
        for (int off = 16; off; off >>= 1) s += __shfl_xor(s, off, 64);
        float ls = logf(s);
        ((float4*)dstrow)[l32] =
            make_float4((v.x - m) - ls, (v.y - m) - ls, (v.z - m) - ls, (v.w - m) - ls);
    };

    // prologue: rows 0..15 -> buf0; rows 16..31 -> R (normalized at top of g=0)
    float4 R = pb4[hw * 32 + l32];
    normrow(R, &prob[0][hw][0]);
    R = pb4[(16 + hw) * 32 + l32];
    __syncthreads();

    const int nG = (len + 15) >> 4;
    for (int g = 0; g < nG; ++g) {
        const int tb = g << 4;
        // Pv register prefetch for the whole group (written during g-1, synced)
        float Pg[16];
#pragma unroll
        for (int k2 = 0; k2 < 16; ++k2) Pg[k2] = prob[g & 1][k2][cur];
        // normalize rows of group g+1 (loaded last group) -> buf[(g+1)&1].
        normrow(R, &prob[(g + 1) & 1][hw][0]);
        // issue raw loads for group g+2 (stay in flight across step barriers)
        {
            int rr = tb + 32 + hw;
            if (rr > TT - 1) rr = TT - 1;   // clamped row never normalized/used
            R = pb4[rr * 32 + l32];
        }
#pragma unroll 4
        for (int k = 0; k < 16; ++k) {
            const int t = tb + k;
            if (t < len) {                         // uniform per block
                const float* ra = alpha[t & 1];
                float*       wa = alpha[(t & 1) ^ 1];
                const float4* a4 = (const float4*)(ra + q * 36);  // banks 0/4/8/12 per quarter
                // 32 adds (same values as proven serial version)
                float v[32];
#pragma unroll
                for (int i = 0; i < 8; ++i) {
                    float4 a = a4[i];
                    v[4*i+0] = a.x + tr[4*i+0];
                    v[4*i+1] = a.y + tr[4*i+1];
                    v[4*i+2] = a.z + tr[4*i+2];
                    v[4*i+3] = a.w + tr[4*i+3];
                }
                // (val,idx) tree, strict > toward the right (higher-index) arm:
                // == lowest-index-among-maxima == proven serial first-max.
                float m1[16]; int i1[16];
#pragma unroll
                for (int j = 0; j < 16; ++j) {
                    bool tk = v[2*j+1] > v[2*j];
                    m1[j] = tk ? v[2*j+1] : v[2*j];
                    i1[j] = tk ? 2*j+1 : 2*j;
                }
                float m2[8]; int i2[8];
#pragma unroll
                for (int j = 0; j < 8; ++j) {
                    bool tk = m1[2*j+1] > m1[2*j];
                    m2[j] = tk ? m1[2*j+1] : m1[2*j];
                    i2[j] = tk ? i1[2*j+1] : i1[2*j];
                }
                float m3[4]; int i3[4];
#pragma unroll
                for (int j = 0; j < 4; ++j) {
                    bool tk = m2[2*j+1] > m2[2*j];
                    m3[j] = tk ? m2[2*j+1] : m2[2*j];
                    i3[j] = tk ? i2[2*j+1] : i2[2*j];
                }
                float m4[2]; int i4[2];
#pragma unroll
                for (int j = 0; j < 2; ++j) {
                    bool tk = m3[2*j+1] > m3[2*j];
                    m4[j] = tk ? m3[2*j+1] : m3[2*j];
                    i4[j] = tk ? i3[2*j+1] : i3[2*j];
                }
                bool tk5 = m4[1] > m4[0];
                float best = tk5 ? m4[1] : m4[0];
                int   bp   = (tk5 ? i4[1] : i4[0]) + q * 32;   // absolute prev index

                // DPP quad combine (value + index). Tie-break identical to proven:
                // even q: strict > keeps own (lower prev range); odd q: >= takes lower partner.
                float v1 = dpp_xor1_f(best); int b1 = dpp_xor1_i(bp);
                bool  t1 = (q & 1) ? (v1 >= best) : (v1 > best);
                float mm1 = t1 ? v1 : best;  int p1 = t1 ? b1 : bp;
                float v2 = dpp_xor2_f(mm1);  int b2 = dpp_xor2_i(p1);
                bool  t2 = (q & 2) ? (v2 >= mm1) : (v2 > mm1);
                float M  = t2 ? v2 : mm1;    int BP = t2 ? b2 : p1;

                if (q == 0) {
                    wa[ASLOT(cur)] = M + Pg[k];
                    if (t >= 1) {
                        if (t < TSPLIT) bps[(t - 1) * NN + cur] = (unsigned char)BP;
                        else if (USE_WS) spb[(t - TSPLIT) * NN + cur] = (unsigned char)BP;
                        else             spb[(size_t)t * 512 + cur] = (unsigned char)BP;
                    }
                }
                STEP_BARRIER();    // lgkmcnt(0) only — global prefetch stays in flight
            }
        }
    }

    __threadfence();   // spilled bp global writes visible to this block's readers

    // terminal: argmax(alpha + trans0[EOS][:]), first-max tie-break
    if (tid < NN) {
        float v = alpha[len & 1][ASLOT(tid)] + trans[EOS_IDX * NN + tid];
        int idx = tid;
#pragma unroll
        for (int off = 32; off; off >>= 1) {
            float ov = __shfl_xor(v, off, 64);
            int   oi = __shfl_xor(idx, off, 64);
            if (ov > v || (ov == v && oi < idx)) { v = ov; idx = oi; }
        }
        if (lane == 0) { fin_v[wave] = v; fin_i[wave] = idx; }
    }
    __syncthreads();   // fin ready; full drain (incl. vmcnt) of forward traffic

    const int lenU = __builtin_amdgcn_readfirstlane(len);

    for (int t = lenU + tid; t < TT; t += 512) out[(size_t)b * TT + t] = 0.0f;

    // stage spilled bp steps [TSPLIT, TSPLIT+128) into the (now free) prob LDS.
    {
        unsigned int* cache = (unsigned int*)&prob[0][0][0];          // 16384 B, exact fit
        const volatile unsigned int* src = (const volatile unsigned int*)spb;
        for (int i = tid; i < 128 * 32; i += 512) {
            if (USE_WS) cache[i] = src[(size_t)(i >> 5) * 32 + (i & 31)];
            else        cache[i] = src[(size_t)(TSPLIT + (i >> 5)) * 128 + (i & 31)];
        }
    }
    __syncthreads();

    // terminal winner (uniform across threads)
    float sc; int T0;
    {
        float v0 = fin_v[0], v1 = fin_v[1];
        int   i0 = fin_i[0], i1 = fin_i[1];
        if (v1 > v0) { sc = v1; T0 = i1; }
        else         { sc = v0; T0 = i0; }
    }
    if (tid == 0) {
        out[(size_t)BB * TT + b] = sc;
        out[(size_t)b * TT + (lenU - 1)] = (float)T0;
    }

    // ---------- parallel hypothesis backtrace ----------
    // 8 segments of 64 links; wave s chases segment s for all 128 entry tags
    // (2 hypotheses/lane), replaying the exact same byte loads as a serial chase.
    const unsigned char* cacheb = (const unsigned char*)&prob[0][0][0];
    unsigned char* lt   = (unsigned char*)&alpha[0][0];   // last_tag[8][128] overlay (alpha dead)
    unsigned char* Harr = lt + 1024;                      // H[8] overlay

    const int s  = wave;                   // segment id 0..7
    const int A  = lenU - 1 - 64 * s;      // anchor time of this segment
    const int h0 = lane;                   // hypothesis tags
    const int h1 = 64 + lane;
    const int Jmax = (A < 64) ? A : 64;    // links to follow (A<1 -> none)

    unsigned int rec0[16], rec1[16];
#pragma unroll
    for (int i = 0; i < 16; ++i) { rec0[i] = 0u; rec1[i] = 0u; }

    int c0 = h0, c1 = h1;
#pragma unroll
    for (int j = 1; j <= 64; ++j) {
        if (j <= Jmax) {                   // wave-uniform
            const int x = A - j + 1;       // step whose bp we read -> tag at time A-j
            int n0, n1;
            if (x < TSPLIT) {
                n0 = bps[(x - 1) * NN + c0];
                n1 = bps[(x - 1) * NN + c1];
            } else if (x < TSPLIT + 128) {
                n0 = cacheb[(x - TSPLIT) * NN + c0];
                n1 = cacheb[(x - TSPLIT) * NN + c1];
            } else {
                if (USE_WS) {
                    n0 = ((const volatile unsigned char*)spb)[(size_t)(x - TSPLIT) * NN + c0];
                    n1 = ((const volatile unsigned char*)spb)[(size_t)(x - TSPLIT) * NN + c1];
                } else {
                    n0 = ((const volatile unsigned char*)spb)[(size_t)x * 512 + c0];
                    n1 = ((const volatile unsigned char*)spb)[(size_t)x * 512 + c1];
                }
            }
            c0 = n0; c1 = n1;
            rec0[(j - 1) >> 2] |= (unsigned int)c0 << (((j - 1) & 3) * 8);
            rec1[(j - 1) >> 2] |= (unsigned int)c1 << (((j - 1) & 3) * 8);
        }
    }
    if (A >= 65) {                         // tag at A-64 feeds segment s+1's stitch
        lt[s * NN + h0] = (unsigned char)c0;
        lt[s * NN + h1] = (unsigned char)c1;
    }
    __syncthreads();

    if (tid == 0) {
        int H = T0;
        Harr[0] = (unsigned char)H;
#pragma unroll
        for (int ss = 1; ss < 8; ++ss) {
            if (lenU - 1 - 64 * ss >= 1) {
                H = lt[(ss - 1) * NN + H];
                Harr[ss] = (unsigned char)H;
            }
        }
    }
    __syncthreads();

    if (A >= 1) {
        const int Hs = Harr[s];
        if (h0 == Hs) {
#pragma unroll
            for (int j = 1; j <= 64; ++j)
                if (j <= Jmax)
                    out[(size_t)b * TT + (A - j)] =
                        (float)((rec0[(j - 1) >> 2] >> (((j - 1) & 3) * 8)) & 255u);
        }
        if (h1 == Hs) {
#pragma unroll
            for (int j = 1; j <= 64; ++j)
                if (j <= Jmax)
                    out[(size_t)b * TT + (A - j)] =
                        (float)((rec1[(j - 1) >> 2] >> (((j - 1) & 3) * 8)) & 255u);
        }
    }
}

extern "C" void kernel_launch(void* const* d_in, const int* in_sizes, int n_in,
                              void* d_out, int out_size, void* d_ws, size_t ws_size,
                              hipStream_t stream) {
    float*       unaries = (float*)d_in[0];
    const float* trans   = (const float*)d_in[1];
    const int*   lengths = (const int*)d_in[2];
    float* out = (float*)d_out;
    unsigned char* ws = (unsigned char*)d_ws;

    const size_t need = (size_t)BB * (TT - TSPLIT) * NN;   // 4,718,592 B
    if (ws != nullptr && ws_size >= need) {
        hipLaunchKernelGGL(HIP_KERNEL_NAME(viterbi_kernel<1>), dim3(BB), dim3(512), 0, stream,
                           unaries, trans, lengths, out, ws);
    } else {
        hipLaunchKernelGGL(HIP_KERNEL_NAME(viterbi_kernel<0>), dim3(BB), dim3(512), 0, stream,
                           unaries, trans, lengths, out, ws);
    }
}